// Round 6
// baseline (800.155 us; speedup 1.0000x reference)
//
#include <hip/hip_runtime.h>

#define NS 7
#define NA 131072
#define AEVD 1008
#define KP1 1024
#define N1 256
#define N2 192
#define N3 160
#define HP 264   // wave-private h pitch (u16); 528B rows -> even bank spread

typedef __attribute__((ext_vector_type(8))) short short8;
typedef __attribute__((ext_vector_type(8))) unsigned short ushortx8;
typedef __attribute__((ext_vector_type(4))) unsigned short ushortx4;
typedef __attribute__((ext_vector_type(2))) unsigned int u32x2;
typedef __attribute__((ext_vector_type(2))) float f32x2;
typedef __attribute__((ext_vector_type(4))) float f32x4;
typedef __attribute__((ext_vector_type(4))) float fvec4;
typedef unsigned short u16;

__device__ __forceinline__ u16 f2bf(float f) {
  unsigned u = __builtin_bit_cast(unsigned, f);
  u += 0x7fffu + ((u >> 16) & 1u);
  return (u16)(u >> 16);
}
__device__ __forceinline__ unsigned pk2(float a, float b) {
  return (unsigned)f2bf(a) | ((unsigned)f2bf(b) << 16);
}
__device__ __forceinline__ float bf2f(u16 h) {
  return __builtin_bit_cast(float, ((unsigned)h) << 16);
}
__device__ __forceinline__ float celu_f(float x) {
  return x > 0.f ? x : 0.1f * (__expf(x * 10.f) - 1.f);
}

// ---------------- bucketing ----------------
__global__ void count_kernel(const int* __restrict__ species, int* __restrict__ counts) {
  __shared__ int h[NS];
  if (threadIdx.x < NS) h[threadIdx.x] = 0;
  __syncthreads();
  int i = blockIdx.x * blockDim.x + threadIdx.x;
  if (i < NA) atomicAdd(&h[species[i]], 1);
  __syncthreads();
  if (threadIdx.x < NS) atomicAdd(&counts[threadIdx.x], h[threadIdx.x]);
}

__global__ void scan_kernel(const int* __restrict__ counts, int* __restrict__ offsets,
                            int* __restrict__ cursors, int* __restrict__ gstart) {
  int off = 0, gs = 0;
  for (int e = 0; e < NS; ++e) {
    offsets[e] = off; cursors[e] = off; gstart[e] = gs;
    off += counts[e];
    gs += (counts[e] + 15) >> 4;
  }
  offsets[NS] = off; gstart[NS] = gs;
}

__global__ void scatter_kernel(const int* __restrict__ species, int* __restrict__ cursors,
                               int* __restrict__ idx) {
  __shared__ int h[NS], lb[NS];
  if (threadIdx.x < NS) h[threadIdx.x] = 0;
  __syncthreads();
  int i = blockIdx.x * blockDim.x + threadIdx.x;
  int s = species[i];
  int lpos = atomicAdd(&h[s], 1);
  __syncthreads();
  if (threadIdx.x < NS) lb[threadIdx.x] = atomicAdd(&cursors[threadIdx.x], h[threadIdx.x]);
  __syncthreads();
  idx[lb[s] + lpos] = i;
}

// ---------------- weight convert: dst[e][n][kp] = bf16(src[e][k][n]) ----------------
__global__ void convert_w(const float* __restrict__ src, u16* __restrict__ dst,
                          int K, int N, int KP) {
  long total = (long)NS * N * KP;
  for (long i = (long)blockIdx.x * blockDim.x + threadIdx.x; i < total;
       i += (long)gridDim.x * blockDim.x) {
    int kp = (int)(i % KP);
    long t2 = i / KP;
    int n = (int)(t2 % N);
    int e = (int)(t2 / N);
    float v = (kp < K) ? src[((long)e * K + kp) * N + n] : 0.f;
    dst[i] = f2bf(v);
  }
}

// ---------------- fused MLP: wave-independent, zero barriers ----------------
__global__ __launch_bounds__(256, 4) void ani_fused(
    const int* __restrict__ idx, const int* __restrict__ counts,
    const int* __restrict__ offsets, const int* __restrict__ gstart,
    const float* __restrict__ aev,
    const u16* __restrict__ W1t, const float* __restrict__ b1,
    const u16* __restrict__ W2t, const float* __restrict__ b2,
    const u16* __restrict__ W3t, const float* __restrict__ b3,
    const u16* __restrict__ Wht, const float* __restrict__ bh,
    float* __restrict__ out) {
  __shared__ __align__(16) u16 HL[4][16 * HP];   // 8448 B per wave

  int tid = threadIdx.x;
  int w = tid >> 6, lane = tid & 63;
  int lr = lane & 15, kg = lane >> 4;
  int g = blockIdx.x * 4 + w;
  if (g >= gstart[NS]) return;   // whole-wave exit; no barriers anywhere
  int e = 0;
#pragma unroll
  for (int s = 1; s < NS; ++s)
    if (g >= gstart[s]) e = s;
  int t = g - gstart[e];
  int base = offsets[e] + t * 16;
  int mcount = counts[e] - t * 16;
  if (mcount > 16) mcount = 16;
  int rrow = lr < mcount ? lr : mcount - 1;
  const float* aevRow = aev + (size_t)idx[base + rrow] * AEVD;
  u16* H = HL[w];

  // ---------- layer 1: swapped mfma(W1frag, aevfrag) -> acc1[ni] = h1[m=lr][16ni+4kg+r]
  const u16* wb1 = W1t + ((size_t)e * N1 + lr) * KP1 + kg * 8;
  f32x4 acc1[16] = {};
  fvec4 pa[2], pb[2];

  auto loadA = [&](int c, fvec4 (&p)[2]) {
    int k = c * 32 + kg * 8;
    if (k < AEVD) {
      p[0] = *(const fvec4*)(aevRow + k);
      p[1] = *(const fvec4*)(aevRow + k + 4);
    } else {
      fvec4 z = {0.f, 0.f, 0.f, 0.f};
      p[0] = z; p[1] = z;
    }
  };
  auto chunk1 = [&](int c, fvec4 (&p)[2]) {
    ushortx8 yy;
    yy[0] = f2bf(p[0].x); yy[1] = f2bf(p[0].y); yy[2] = f2bf(p[0].z); yy[3] = f2bf(p[0].w);
    yy[4] = f2bf(p[1].x); yy[5] = f2bf(p[1].y); yy[6] = f2bf(p[1].z); yy[7] = f2bf(p[1].w);
    short8 y = __builtin_bit_cast(short8, yy);
    if (c + 2 < 32) loadA(c + 2, p);   // refill this buffer 2 chunks ahead
    const u16* wb = wb1 + c * 32;
#pragma unroll
    for (int nb = 0; nb < 4; ++nb) {
      short8 x[4];
#pragma unroll
      for (int j = 0; j < 4; ++j)
        x[j] = *(const short8*)(wb + (size_t)(nb * 4 + j) * 16 * KP1);
#pragma unroll
      for (int j = 0; j < 4; ++j)
        acc1[nb * 4 + j] = __builtin_amdgcn_mfma_f32_16x16x32_bf16(x[j], y, acc1[nb * 4 + j], 0, 0, 0);
    }
  };

  loadA(0, pa);
  loadA(1, pb);
  for (int c = 0; c < 32; c += 2) {
    chunk1(c, pa);
    chunk1(c + 1, pb);
  }

  // epilogue 1 -> wave-private H (rows m=lr): bias+celu+pack, b64 writes
#pragma unroll
  for (int ni = 0; ni < 16; ++ni) {
    fvec4 bv = *(const fvec4*)(b1 + e * N1 + ni * 16 + kg * 4);
    u32x2 q;
    q[0] = pk2(celu_f(acc1[ni][0] + bv[0]), celu_f(acc1[ni][1] + bv[1]));
    q[1] = pk2(celu_f(acc1[ni][2] + bv[2]), celu_f(acc1[ni][3] + bv[3]));
    *(u32x2*)&H[lr * HP + ni * 16 + kg * 4] = q;
  }

  // ---------- layer 2: X=W2frag, Y=h1 from LDS (lane m=lr, k-window) ----------
  const u16* wb2 = W2t + ((size_t)e * N2 + lr) * N1 + kg * 8;
  f32x4 acc2[12] = {};
#pragma unroll
  for (int ks = 0; ks < 8; ++ks) {
    short8 y = *(const short8*)&H[lr * HP + ks * 32 + kg * 8];
#pragma unroll
    for (int ni = 0; ni < 12; ++ni) {
      short8 x = *(const short8*)(wb2 + (size_t)ni * 16 * N1 + ks * 32);
      acc2[ni] = __builtin_amdgcn_mfma_f32_16x16x32_bf16(x, y, acc2[ni], 0, 0, 0);
    }
  }

  // epilogue 2 -> same H buffer (all h1 reads are earlier in program order; lgkm ordering)
#pragma unroll
  for (int ni = 0; ni < 12; ++ni) {
    fvec4 bv = *(const fvec4*)(b2 + e * N2 + ni * 16 + kg * 4);
    u32x2 q;
    q[0] = pk2(celu_f(acc2[ni][0] + bv[0]), celu_f(acc2[ni][1] + bv[1]));
    q[1] = pk2(celu_f(acc2[ni][2] + bv[2]), celu_f(acc2[ni][3] + bv[3]));
    *(u32x2*)&H[lr * HP + ni * 16 + kg * 4] = q;
  }

  // ---------- layer 3: X=W3frag, Y=h2 from LDS ----------
  const u16* wb3 = W3t + ((size_t)e * N3 + lr) * N2 + kg * 8;
  f32x4 acc3[10] = {};
#pragma unroll
  for (int ks = 0; ks < 6; ++ks) {
    short8 y = *(const short8*)&H[lr * HP + ks * 32 + kg * 8];
#pragma unroll
    for (int ni = 0; ni < 10; ++ni) {
      short8 x = *(const short8*)(wb3 + (size_t)ni * 16 * N2 + ks * 32);
      acc3[ni] = __builtin_amdgcn_mfma_f32_16x16x32_bf16(x, y, acc3[ni], 0, 0, 0);
    }
  }

  // ---------- head: fully in-register; reduce over kg via shuffles ----------
  float s0 = 0.f, s1 = 0.f;
#pragma unroll
  for (int ni = 0; ni < 10; ++ni) {
    fvec4 bv = *(const fvec4*)(b3 + e * N3 + ni * 16 + kg * 4);
    ushortx4 w0 = *(const ushortx4*)(Wht + ((size_t)e * 2 + 0) * N3 + ni * 16 + kg * 4);
    ushortx4 w1 = *(const ushortx4*)(Wht + ((size_t)e * 2 + 1) * N3 + ni * 16 + kg * 4);
#pragma unroll
    for (int r = 0; r < 4; ++r) {
      float v = celu_f(acc3[ni][r] + bv[r]);
      s0 += v * bf2f(w0[r]);
      s1 += v * bf2f(w1[r]);
    }
  }
  s0 += __shfl_xor(s0, 16); s0 += __shfl_xor(s0, 32);
  s1 += __shfl_xor(s1, 16); s1 += __shfl_xor(s1, 32);
  if (kg == 0 && lr < mcount) {
    f32x2 o2 = {s0 + bh[e * 2], s1 + bh[e * 2 + 1]};
    *(f32x2*)(out + (size_t)idx[base + lr] * 2) = o2;
  }
}

extern "C" void kernel_launch(void* const* d_in, const int* in_sizes, int n_in,
                              void* d_out, int out_size, void* d_ws, size_t ws_size,
                              hipStream_t stream) {
  const int* species = (const int*)d_in[0];
  const float* aev = (const float*)d_in[1];
  const float* W1 = (const float*)d_in[2];
  const float* b1 = (const float*)d_in[3];
  const float* W2 = (const float*)d_in[4];
  const float* b2 = (const float*)d_in[5];
  const float* W3 = (const float*)d_in[6];
  const float* b3 = (const float*)d_in[7];
  const float* Wh = (const float*)d_in[8];
  const float* bh = (const float*)d_in[9];
  float* out = (float*)d_out;

  char* p = (char*)d_ws;
  int* counts = (int*)p; p += 32;
  int* offsets = (int*)p; p += 32;
  int* cursors = (int*)p; p += 32;
  int* gstart = (int*)p; p += 32;
  int* idx = (int*)p; p += (size_t)NA * 4;
  u16* W1t = (u16*)p; p += (size_t)NS * N1 * KP1 * 2;
  u16* W2t = (u16*)p; p += (size_t)NS * N2 * N1 * 2;
  u16* W3t = (u16*)p; p += (size_t)NS * N3 * N2 * 2;
  u16* Wht = (u16*)p; p += (size_t)NS * 2 * N3 * 2;

  (void)hipMemsetAsync(counts, 0, 32, stream);
  count_kernel<<<NA / 256, 256, 0, stream>>>(species, counts);
  scan_kernel<<<1, 1, 0, stream>>>(counts, offsets, cursors, gstart);
  scatter_kernel<<<NA / 256, 256, 0, stream>>>(species, cursors, idx);

  convert_w<<<2048, 256, 0, stream>>>(W1, W1t, AEVD, N1, KP1);
  convert_w<<<1024, 256, 0, stream>>>(W2, W2t, N1, N2, N1);
  convert_w<<<512, 256, 0, stream>>>(W3, W3t, N2, N3, N2);
  convert_w<<<16, 256, 0, stream>>>(Wh, Wht, N3, 2, N3);

  int ngroups = NA / 16 + NS;            // upper bound on sum ceil(counts/16)
  int blocks = (ngroups + 3) / 4;
  ani_fused<<<blocks, 256, 0, stream>>>(idx, counts, offsets, gstart, aev,
                                        W1t, b1, W2t, b2, W3t, b3, Wht, bh, out);
}

// Round 7
// 422.831 us; speedup vs baseline: 1.8924x; 1.8924x over previous
//
#include <hip/hip_runtime.h>

#define NS 7
#define NA 131072
#define AEVD 1008
#define KP1 1024
#define N1 256
#define N2 192
#define N3 160

#define H1P 272   // u16 pitch
#define H2P 208   // u16 pitch
#define ABUF_BYTES 8192   // 64 rows x 128 B (32 fp32)

typedef __attribute__((ext_vector_type(8))) short short8;
typedef __attribute__((ext_vector_type(8))) unsigned short ushortx8;
typedef __attribute__((ext_vector_type(4))) float f32x4;
typedef __attribute__((ext_vector_type(4))) float fvec4;
typedef unsigned short u16;
typedef unsigned int u32;

// counted-vmcnt barrier: A-stage gl_lds loads stay in flight (T4); lgkmcnt(0)
// orders ds_reads for the buffer-reuse WAR.
#define BARV14() asm volatile("s_waitcnt vmcnt(14) lgkmcnt(0)\ns_barrier" ::: "memory")
#define BARV8()  asm volatile("s_waitcnt vmcnt(8) lgkmcnt(0)\ns_barrier" ::: "memory")

__device__ __forceinline__ u16 f2bf(float f) {
  unsigned u = __builtin_bit_cast(unsigned, f);
  u += 0x7fffu + ((u >> 16) & 1u);
  return (u16)(u >> 16);
}
__device__ __forceinline__ float bf2f(u16 h) {
  return __builtin_bit_cast(float, ((unsigned)h) << 16);
}
__device__ __forceinline__ float celu_f(float x) {
  return x > 0.f ? x : 0.1f * (__expf(x * 10.f) - 1.f);
}
__device__ __forceinline__ void gload_lds16(const void* src, void* lds) {
  __builtin_amdgcn_global_load_lds(
      (const __attribute__((address_space(1))) u32*)src,
      (__attribute__((address_space(3))) u32*)lds, 16, 0, 0);
}

// ---------------- bucketing ----------------
__global__ void count_kernel(const int* __restrict__ species, int* __restrict__ counts) {
  __shared__ int h[NS];
  if (threadIdx.x < NS) h[threadIdx.x] = 0;
  __syncthreads();
  int i = blockIdx.x * blockDim.x + threadIdx.x;
  if (i < NA) atomicAdd(&h[species[i]], 1);
  __syncthreads();
  if (threadIdx.x < NS) atomicAdd(&counts[threadIdx.x], h[threadIdx.x]);
}

__global__ void scan_kernel(const int* __restrict__ counts, int* __restrict__ offsets,
                            int* __restrict__ cursors, int* __restrict__ blockStart) {
  int off = 0, bs = 0;
  for (int e = 0; e < NS; ++e) {
    offsets[e] = off; cursors[e] = off; blockStart[e] = bs;
    off += counts[e];
    bs += (counts[e] + 63) >> 6;
  }
  offsets[NS] = off; blockStart[NS] = bs;
}

__global__ void scatter_kernel(const int* __restrict__ species, int* __restrict__ cursors,
                               int* __restrict__ idx) {
  __shared__ int h[NS], lb[NS];
  if (threadIdx.x < NS) h[threadIdx.x] = 0;
  __syncthreads();
  int i = blockIdx.x * blockDim.x + threadIdx.x;
  int s = species[i];
  int lpos = atomicAdd(&h[s], 1);
  __syncthreads();
  if (threadIdx.x < NS) lb[threadIdx.x] = atomicAdd(&cursors[threadIdx.x], h[threadIdx.x]);
  __syncthreads();
  idx[lb[s] + lpos] = i;
}

// ---------------- weight convert: dst[e][n][kp] = bf16(src[e][k][n]), zero pad ----------------
__global__ void convert_w(const float* __restrict__ src, u16* __restrict__ dst,
                          int K, int N, int KP) {
  long total = (long)NS * N * KP;
  for (long i = (long)blockIdx.x * blockDim.x + threadIdx.x; i < total;
       i += (long)gridDim.x * blockDim.x) {
    int kp = (int)(i % KP);
    long t2 = i / KP;
    int n = (int)(t2 % N);
    int e = (int)(t2 / N);
    float v = (kp < K) ? src[((long)e * K + kp) * N + n] : 0.f;
    dst[i] = f2bf(v);
  }
}

// ---------------- fused MLP ----------------
__global__ __launch_bounds__(256, 2) void ani_fused(
    const int* __restrict__ idx, const int* __restrict__ counts,
    const int* __restrict__ offsets, const int* __restrict__ blockStart,
    const float* __restrict__ aev,
    const u16* __restrict__ W1t, const float* __restrict__ b1,
    const u16* __restrict__ W2t, const float* __restrict__ b2,
    const u16* __restrict__ W3t, const float* __restrict__ b3,
    const u16* __restrict__ Wht, const float* __restrict__ bh,
    float* __restrict__ out) {
  // [0,32768): A-bufs x4 (fp32, linear for gl_lds), later H2 (64 x H2P u16)
  // [32768, 32768+34816): H1 (64 x H1P u16)
  __shared__ __align__(16) unsigned char LDS[32768 + 34816];
  u16* H1 = (u16*)(LDS + 32768);
  u16* H2 = (u16*)LDS;

  int bid = blockIdx.x;
  if (bid >= blockStart[NS]) return;   // block-uniform exit
  int e = 0;
#pragma unroll
  for (int s = 1; s < NS; ++s)
    if (bid >= blockStart[s]) e = s;
  int t0 = bid - blockStart[e];
  int base = offsets[e] + (t0 << 6);
  int mcount = counts[e] - (t0 << 6);
  if (mcount > 64) mcount = 64;

  int tid = threadIdx.x;
  int lane = tid & 63;
  int w = tid >> 6;      // wave 0..3
  int lr = lane & 15;
  int kg = lane >> 4;

  // ---- A staging (fp32 via global_load_lds, source pre-swizzled) ----
  int slot = lane & 7;                 // 16B slot within 128B row
  int srow0 = w * 16 + (lane >> 3);    // call-0 row, call-1 = +8
  int srow1 = srow0 + 8;
  int rr0 = srow0 < mcount ? srow0 : mcount - 1;
  int rr1 = srow1 < mcount ? srow1 : mcount - 1;
  const float* sp0 = aev + (size_t)idx[base + rr0] * AEVD;
  const float* sp1 = aev + (size_t)idx[base + rr1] * AEVD;
  int soff = (slot ^ ((srow0 & 3) << 1)) * 4;   // srow1&3 == srow0&3

  auto stageA = [&](int c) {
    int off = c * 32 + ((c == 31 && soff > 12) ? 12 : soff);
    unsigned char* lbase = LDS + (c & 3) * ABUF_BYTES + w * 2048;
    gload_lds16(sp0 + off, lbase);
    gload_lds16(sp1 + off, lbase + 1024);
  };

  // ---- layer 1: [64 x 1024] @ [1024 x 256], N-split 64 cols/wave ----
  const u16* Wb1 = W1t + ((size_t)e * N1 + (w * 64 + lr)) * KP1 + kg * 8;
  f32x4 acc1[4][4] = {};
  short8 rbA[4], rbB[4];
  auto loadB1 = [&](int c, short8 (&r)[4]) {
#pragma unroll
    for (int ni = 0; ni < 4; ++ni)
      r[ni] = *(const short8*)(Wb1 + (size_t)ni * 16 * KP1 + c * 32);
  };
  auto iterA = [&](int t, short8 (&r)[4]) {
    const unsigned char* ab = LDS + (t & 3) * ABUF_BYTES;
    short8 af[4];
#pragma unroll
    for (int mi = 0; mi < 4; ++mi) {
      int R = mi * 16 + lr;
      int bo = R * 128 + (((2 * kg) ^ ((R & 3) << 1)) * 16);
      fvec4 f0 = *(const fvec4*)(ab + bo);
      fvec4 f1 = *(const fvec4*)(ab + bo + 16);
      ushortx8 pk;
      pk[0] = f2bf(f0.x); pk[1] = f2bf(f0.y); pk[2] = f2bf(f0.z); pk[3] = f2bf(f0.w);
      pk[4] = f2bf(f1.x); pk[5] = f2bf(f1.y); pk[6] = f2bf(f1.z); pk[7] = f2bf(f1.w);
      af[mi] = __builtin_bit_cast(short8, pk);
    }
#pragma unroll
    for (int ni = 0; ni < 4; ++ni)
#pragma unroll
      for (int mi = 0; mi < 4; ++mi)
        acc1[mi][ni] = __builtin_amdgcn_mfma_f32_16x16x32_bf16(af[mi], r[ni], acc1[mi][ni], 0, 0, 0);
  };

  // prologue: A first (so vmcnt(14) exactly drains through A(t)), then B ring
  stageA(0); stageA(1); stageA(2);
  loadB1(0, rbA); loadB1(1, rbB);

  for (int tt = 0; tt < 16; ++tt) {
    int t = tt * 2;
    if (t + 3 < 32) stageA(t + 3);
    BARV14();
    iterA(t, rbA);
    if (t + 2 < 32) loadB1(t + 2, rbA);
    int t1 = t + 1;
    if (t1 + 3 < 32) stageA(t1 + 3);
    if (t1 == 31) { BARV8(); } else { BARV14(); }
    iterA(t1, rbB);
    if (t1 + 2 < 32) loadB1(t1 + 2, rbB);
  }

  // ---- layer 2 B ring prefetch (hoisted above epilogue-1) ----
  const u16* Wb2 = W2t + ((size_t)e * N2 + lr) * N1 + kg * 8;
  auto loadB2 = [&](int ks, short8 (&r)[12]) {
#pragma unroll
    for (int ni = 0; ni < 12; ++ni)
      r[ni] = *(const short8*)(Wb2 + (size_t)ni * 16 * N1 + ks * 32);
  };
  short8 r2a[12], r2b[12];
  loadB2(0, r2a); loadB2(1, r2b);

  // epilogue 1 -> H1 (separate region; abuf reads all done at last BARV)
#pragma unroll
  for (int ni = 0; ni < 4; ++ni) {
    int col = w * 64 + ni * 16 + lr;
    float bias = b1[e * N1 + col];
#pragma unroll
    for (int mi = 0; mi < 4; ++mi)
#pragma unroll
      for (int r = 0; r < 4; ++r)
        H1[(mi * 16 + kg * 4 + r) * H1P + col] = f2bf(celu_f(acc1[mi][ni][r] + bias));
  }
  __syncthreads();   // the only barrier after layer 1

  // ---- layer 2: [64 x 256] @ [256 x 192], M-split 16 rows/wave, no barriers ----
  f32x4 acc2[12] = {};
  auto mm2 = [&](int ks, short8 (&r)[12]) {
    short8 a = *(const short8*)&H1[(w * 16 + lr) * H1P + ks * 32 + kg * 8];
#pragma unroll
    for (int ni = 0; ni < 12; ++ni)
      acc2[ni] = __builtin_amdgcn_mfma_f32_16x16x32_bf16(a, r[ni], acc2[ni], 0, 0, 0);
  };
  mm2(0, r2a); loadB2(2, r2a);
  mm2(1, r2b); loadB2(3, r2b);
  mm2(2, r2a); loadB2(4, r2a);
  mm2(3, r2b); loadB2(5, r2b);
  mm2(4, r2a); loadB2(6, r2a);
  mm2(5, r2b); loadB2(7, r2b);
  mm2(6, r2a);
  mm2(7, r2b);

  // ---- layer 3 B ring prefetch (hoisted above epilogue-2) ----
  const u16* Wb3 = W3t + ((size_t)e * N3 + lr) * N2 + kg * 8;
  auto loadB3 = [&](int ks, short8 (&r)[10]) {
#pragma unroll
    for (int ni = 0; ni < 10; ++ni)
      r[ni] = *(const short8*)(Wb3 + (size_t)ni * 16 * N2 + ks * 32);
  };
  short8 r3a[10], r3b[10];
  loadB3(0, r3a); loadB3(1, r3b);

  // epilogue 2 -> H2 (wave-private rows; overlays dead A-bufs; no barrier needed)
#pragma unroll
  for (int ni = 0; ni < 12; ++ni) {
    float bias = b2[e * N2 + ni * 16 + lr];
#pragma unroll
    for (int r = 0; r < 4; ++r)
      H2[(w * 16 + kg * 4 + r) * H2P + ni * 16 + lr] = f2bf(celu_f(acc2[ni][r] + bias));
  }

  // ---- layer 3: [64 x 192] @ [192 x 160], M-split, wave-private, no barriers ----
  f32x4 acc3[10] = {};
  auto mm3 = [&](int ks, short8 (&r)[10]) {
    short8 a = *(const short8*)&H2[(w * 16 + lr) * H2P + ks * 32 + kg * 8];
#pragma unroll
    for (int ni = 0; ni < 10; ++ni)
      acc3[ni] = __builtin_amdgcn_mfma_f32_16x16x32_bf16(a, r[ni], acc3[ni], 0, 0, 0);
  };
  mm3(0, r3a); loadB3(2, r3a);
  mm3(1, r3b); loadB3(3, r3b);
  mm3(2, r3a); loadB3(4, r3a);
  mm3(3, r3b); loadB3(5, r3b);
  mm3(4, r3a);
  mm3(5, r3b);

  // ---- head: in-register, reduce over lr (16-lane group) ----
  float s0[4] = {0.f, 0.f, 0.f, 0.f};
  float s1[4] = {0.f, 0.f, 0.f, 0.f};
#pragma unroll
  for (int ni = 0; ni < 10; ++ni) {
    int col = ni * 16 + lr;
    float bias = b3[e * N3 + col];
    float w0 = bf2f(Wht[((size_t)e * 2 + 0) * N3 + col]);
    float w1 = bf2f(Wht[((size_t)e * 2 + 1) * N3 + col]);
#pragma unroll
    for (int r = 0; r < 4; ++r) {
      float v = celu_f(acc3[ni][r] + bias);
      s0[r] += v * w0;
      s1[r] += v * w1;
    }
  }
#pragma unroll
  for (int r = 0; r < 4; ++r) {
    s0[r] += __shfl_xor(s0[r], 1); s0[r] += __shfl_xor(s0[r], 2);
    s0[r] += __shfl_xor(s0[r], 4); s0[r] += __shfl_xor(s0[r], 8);
    s1[r] += __shfl_xor(s1[r], 1); s1[r] += __shfl_xor(s1[r], 2);
    s1[r] += __shfl_xor(s1[r], 4); s1[r] += __shfl_xor(s1[r], 8);
  }
  if (lr == 0) {
    float bh0 = bh[e * 2], bh1 = bh[e * 2 + 1];
#pragma unroll
    for (int r = 0; r < 4; ++r) {
      int atom = w * 16 + kg * 4 + r;
      if (atom < mcount) {
        size_t o = (size_t)idx[base + atom] * 2;
        out[o] = s0[r] + bh0;
        out[o + 1] = s1[r] + bh1;
      }
    }
  }
}

extern "C" void kernel_launch(void* const* d_in, const int* in_sizes, int n_in,
                              void* d_out, int out_size, void* d_ws, size_t ws_size,
                              hipStream_t stream) {
  const int* species = (const int*)d_in[0];
  const float* aev = (const float*)d_in[1];
  const float* W1 = (const float*)d_in[2];
  const float* b1 = (const float*)d_in[3];
  const float* W2 = (const float*)d_in[4];
  const float* b2 = (const float*)d_in[5];
  const float* W3 = (const float*)d_in[6];
  const float* b3 = (const float*)d_in[7];
  const float* Wh = (const float*)d_in[8];
  const float* bh = (const float*)d_in[9];
  float* out = (float*)d_out;

  char* p = (char*)d_ws;
  int* counts = (int*)p; p += 32;
  int* offsets = (int*)p; p += 32;
  int* cursors = (int*)p; p += 32;
  int* blockStart = (int*)p; p += 32;
  int* idx = (int*)p; p += (size_t)NA * 4;
  u16* W1t = (u16*)p; p += (size_t)NS * N1 * KP1 * 2;
  u16* W2t = (u16*)p; p += (size_t)NS * N2 * N1 * 2;
  u16* W3t = (u16*)p; p += (size_t)NS * N3 * N2 * 2;
  u16* Wht = (u16*)p; p += (size_t)NS * 2 * N3 * 2;

  (void)hipMemsetAsync(counts, 0, 32, stream);
  count_kernel<<<NA / 256, 256, 0, stream>>>(species, counts);
  scan_kernel<<<1, 1, 0, stream>>>(counts, offsets, cursors, blockStart);
  scatter_kernel<<<NA / 256, 256, 0, stream>>>(species, cursors, idx);

  convert_w<<<2048, 256, 0, stream>>>(W1, W1t, AEVD, N1, KP1);
  convert_w<<<1024, 256, 0, stream>>>(W2, W2t, N1, N2, N1);
  convert_w<<<512, 256, 0, stream>>>(W3, W3t, N2, N3, N2);
  convert_w<<<16, 256, 0, stream>>>(Wh, Wht, N3, 2, N3);

  int maxBlocks = (NA >> 6) + NS;
  ani_fused<<<maxBlocks, 256, 0, stream>>>(idx, counts, offsets, blockStart, aev,
                                           W1t, b1, W2t, b2, W3t, b3, Wht, bh, out);
}